// Round 2
// baseline (624.467 us; speedup 1.0000x reference)
//
#include <hip/hip_runtime.h>
#include <stdint.h>

#define BATCH 4
#define SEQ 2048
#define DMODEL 1024
#define NHEADS 16
#define HDIM 64
#define MROWS (BATCH * SEQ)   // 8192
#define QCHUNK 128

typedef float floatx4 __attribute__((ext_vector_type(4)));
typedef __bf16 bf16x8 __attribute__((ext_vector_type(8)));

__device__ __forceinline__ unsigned short f32_to_bf16(float f) {
    union { float f; unsigned int u; } c; c.f = f;
    unsigned int u = c.u;
    unsigned int r = (u + 0x7FFFu + ((u >> 16) & 1u)) >> 16;
    return (unsigned short)r;
}

// async global->LDS 16B per lane (m97 pattern; LDS dest must be lane-linear)
__device__ __forceinline__ void async_ld16(const void* g, void* l) {
    __builtin_amdgcn_global_load_lds(
        (const __attribute__((address_space(1))) unsigned int*)g,
        (__attribute__((address_space(3))) unsigned int*)l, 16, 0, 0);
}

// ---------------------------------------------------------------- convert x
__global__ __launch_bounds__(256) void conv_f32_bf16(
    const float* __restrict__ in, unsigned short* __restrict__ out, int n4) {
    int i = blockIdx.x * 256 + threadIdx.x;
    if (i < n4) {
        float4 v = ((const float4*)in)[i];
        ushort4 o;
        o.x = f32_to_bf16(v.x); o.y = f32_to_bf16(v.y);
        o.z = f32_to_bf16(v.z); o.w = f32_to_bf16(v.w);
        ((ushort4*)out)[i] = o;
    }
}

// ------------------------------------------- transpose+convert W [K,N] -> [N,K] bf16
__global__ __launch_bounds__(256) void transp_conv(
    const float* __restrict__ in, unsigned short* __restrict__ out, int K, int N) {
    __shared__ float tile[32][33];
    int bx = blockIdx.x * 32;  // n
    int by = blockIdx.y * 32;  // k
    int tx = threadIdx.x, ty = threadIdx.y;
#pragma unroll
    for (int i = 0; i < 4; ++i)
        tile[ty + i * 8][tx] = in[(size_t)(by + ty + i * 8) * N + bx + tx];
    __syncthreads();
#pragma unroll
    for (int i = 0; i < 4; ++i)
        out[(size_t)(bx + ty + i * 8) * K + by + tx] = f32_to_bf16(tile[tx][ty + i * 8]);
}

// ------------------------------------- per-head bf16 transpose [T,64] -> [64,T]
__global__ __launch_bounds__(256) void transp_bf16_head(
    const unsigned short* __restrict__ in, unsigned short* __restrict__ out) {
    __shared__ unsigned short tile[32][33];
    const unsigned short* src = in + (size_t)blockIdx.z * SEQ * HDIM;
    unsigned short* dst = out + (size_t)blockIdx.z * SEQ * HDIM;
    int bx = blockIdx.x * 32;  // d block
    int by = blockIdx.y * 32;  // t block
    int tx = threadIdx.x, ty = threadIdx.y;
#pragma unroll
    for (int i = 0; i < 4; ++i)
        tile[ty + i * 8][tx] = src[(size_t)(by + ty + i * 8) * HDIM + bx + tx];
    __syncthreads();
#pragma unroll
    for (int i = 0; i < 4; ++i)
        dst[(size_t)(bx + ty + i * 8) * SEQ + by + tx] = tile[tx][ty + i * 8];
}

// ---------------------------------------------------------------- GEMM (B^T input)
// C[M,N] = A[M,K] * B[K,N] + bias ; Bt is [N,K] bf16.
// LDS layout: lane-linear for global_load_lds; global chunk XOR-swizzled so
// fragment reads are conflict-free: LDS[row][c] = G[row][c ^ ((row>>1)&3)].
template <int EPI>
__global__ __launch_bounds__(256) void gemm_bt(
    const unsigned short* __restrict__ A, const unsigned short* __restrict__ Bt,
    const float* __restrict__ bias, float* __restrict__ Cout,
    unsigned short* __restrict__ Qo, unsigned short* __restrict__ Ko,
    unsigned short* __restrict__ Vo, int M, int N, int K) {
    __shared__ __align__(16) unsigned short As[128 * 32];
    __shared__ __align__(16) unsigned short Bs[128 * 32];
    const int tid = threadIdx.x;
    const int lane = tid & 63;
    const int w = tid >> 6;
    const int wm = w & 1, wn = w >> 1;
    const int quad = lane >> 4, l16 = lane & 15;
    const int m0 = blockIdx.y * 128;
    const int n0 = blockIdx.x * 128;
    const int fsw = (l16 >> 1) & 3;  // fragment-read swizzle key

    floatx4 acc[4][4];
#pragma unroll
    for (int mt = 0; mt < 4; ++mt)
#pragma unroll
        for (int nt = 0; nt < 4; ++nt) acc[mt][nt] = (floatx4){0.f, 0.f, 0.f, 0.f};

    for (int k0 = 0; k0 < K; k0 += 32) {
#pragma unroll
        for (int r = 0; r < 2; ++r) {
            int idx = tid + r * 256;
            int row = idx >> 2;
            int cg = (idx & 3) ^ ((row >> 1) & 3);
            async_ld16(&A[(size_t)(m0 + row) * K + k0 + cg * 8], &As[idx * 8]);
            async_ld16(&Bt[(size_t)(n0 + row) * K + k0 + cg * 8], &Bs[idx * 8]);
        }
        __syncthreads();
        bf16x8 aF[4], bF[4];
#pragma unroll
        for (int mt = 0; mt < 4; ++mt)
            aF[mt] = *(const bf16x8*)&As[(wm * 64 + mt * 16 + l16) * 32 + (quad ^ fsw) * 8];
#pragma unroll
        for (int nt = 0; nt < 4; ++nt)
            bF[nt] = *(const bf16x8*)&Bs[(wn * 64 + nt * 16 + l16) * 32 + (quad ^ fsw) * 8];
#pragma unroll
        for (int mt = 0; mt < 4; ++mt)
#pragma unroll
            for (int nt = 0; nt < 4; ++nt)
                acc[mt][nt] = __builtin_amdgcn_mfma_f32_16x16x32_bf16(
                    aF[mt], bF[nt], acc[mt][nt], 0, 0, 0);
        __syncthreads();
    }

#pragma unroll
    for (int mt = 0; mt < 4; ++mt)
#pragma unroll
        for (int nt = 0; nt < 4; ++nt)
#pragma unroll
            for (int r = 0; r < 4; ++r) {
                int m = m0 + wm * 64 + mt * 16 + quad * 4 + r;
                int n = n0 + wn * 64 + nt * 16 + l16;
                float v = acc[mt][nt][r] + bias[n];
                if (EPI == 1) {
                    Cout[(size_t)m * N + n] = v;
                } else {
                    int sel = n >> 10, c = n & 1023;
                    int head = c >> 6, d = c & 63;
                    int bb = m >> 11, t = m & 2047;
                    unsigned short* dst = sel == 0 ? Qo : (sel == 1 ? Ko : Vo);
                    dst[((((size_t)bb * NHEADS + head) * SEQ + t) << 6) + d] = f32_to_bf16(v);
                }
            }
}

// ---------------------------------------------------------------- flash attention v2
// grid: (SEQ/QCHUNK [reversed], B*H); block 256 = 4 waves; wave owns 32 q-rows.
// Q fragments in registers. K/V register-prefetched. LDS XOR-swizzled (chunk ^= row&7).
__global__ __launch_bounds__(256, 3) void attn_kernel(
    const unsigned short* __restrict__ Qg, const unsigned short* __restrict__ Kg,
    const unsigned short* __restrict__ Vtg, unsigned short* __restrict__ Yatt) {
    __shared__ __align__(16) unsigned short Ks[64 * 64];   // [key][d]
    __shared__ __align__(16) unsigned short VsT[64 * 64];  // [d][key]
    __shared__ __align__(16) unsigned short Ps[4][32 * 64];

    const int tid = threadIdx.x;
    const int lane = tid & 63;
    const int w = tid >> 6;
    const int quad = lane >> 4, l16 = lane & 15;
    const int qc = (SEQ / QCHUNK - 1) - blockIdx.x;  // heaviest blocks first
    const int q0 = qc * QCHUNK;
    const int bh = blockIdx.y;
    const size_t base = (size_t)bh * SEQ * HDIM;
    const int rowb = q0 + w * 32;  // wave's first q-row

    // Q fragments -> registers (one-time, ~16KB/block)
    bf16x8 qf[2][2];
#pragma unroll
    for (int mt = 0; mt < 2; ++mt)
#pragma unroll
        for (int kk = 0; kk < 2; ++kk)
            qf[mt][kk] = *(const bf16x8*)&Qg[base + (size_t)(rowb + mt * 16 + l16) * 64 +
                                             kk * 32 + quad * 8];

    float mI[2][4], lI[2][4];
    floatx4 o[2][4];
#pragma unroll
    for (int mt = 0; mt < 2; ++mt)
#pragma unroll
        for (int r = 0; r < 4; ++r) { mI[mt][r] = -INFINITY; lI[mt][r] = 0.f; }
#pragma unroll
    for (int mt = 0; mt < 2; ++mt)
#pragma unroll
        for (int nt = 0; nt < 4; ++nt) o[mt][nt] = (floatx4){0.f, 0.f, 0.f, 0.f};

    const int kmax = (q0 + QCHUNK) >> 6;  // #64-key tiles
    const int wrow_max = rowb + 31;

    // prefetch tile 0: idx -> row=idx>>3 (0..63), chunk=idx&7
    uint4 pk[2], pv[2];
#pragma unroll
    for (int r = 0; r < 2; ++r) {
        int idx = tid + r * 256;
        int row = idx >> 3, c = idx & 7;
        pk[r] = *(const uint4*)&Kg[base + (size_t)row * 64 + c * 8];
        pv[r] = *(const uint4*)&Vtg[base + (size_t)row * SEQ + c * 8];
    }

    for (int kb = 0; kb < kmax; ++kb) {
        __syncthreads();  // all waves done reading Ks/VsT from previous tile
#pragma unroll
        for (int r = 0; r < 2; ++r) {
            int idx = tid + r * 256;
            int row = idx >> 3, c = idx & 7;
            int csw = c ^ (row & 7);
            *(uint4*)&Ks[row * 64 + csw * 8] = pk[r];
            *(uint4*)&VsT[row * 64 + csw * 8] = pv[r];
        }
        __syncthreads();
        if (kb + 1 < kmax) {
#pragma unroll
            for (int r = 0; r < 2; ++r) {
                int idx = tid + r * 256;
                int row = idx >> 3, c = idx & 7;
                pk[r] = *(const uint4*)&Kg[base + (size_t)((kb + 1) * 64 + row) * 64 + c * 8];
                pv[r] = *(const uint4*)&Vtg[base + (size_t)row * SEQ + (kb + 1) * 64 + c * 8];
            }
        }
        if (kb * 64 > wrow_max) continue;  // fully-masked tile for this wave

        // S = Q K^T : 16 MFMA, b-frags reused across both m-tiles
        floatx4 s[2][4];
#pragma unroll
        for (int mt = 0; mt < 2; ++mt)
#pragma unroll
            for (int nt = 0; nt < 4; ++nt) s[mt][nt] = (floatx4){0.f, 0.f, 0.f, 0.f};
#pragma unroll
        for (int kk = 0; kk < 2; ++kk)
#pragma unroll
            for (int nt = 0; nt < 4; ++nt) {
                bf16x8 b = *(const bf16x8*)&Ks[(nt * 16 + l16) * 64 +
                                               ((kk * 4 + quad) ^ (l16 & 7)) * 8];
#pragma unroll
                for (int mt = 0; mt < 2; ++mt)
                    s[mt][nt] = __builtin_amdgcn_mfma_f32_16x16x32_bf16(
                        qf[mt][kk], b, s[mt][nt], 0, 0, 0);
            }

        const bool diag = ((kb * 64 + 63) > rowb);  // masking possibly needed
#pragma unroll
        for (int mt = 0; mt < 2; ++mt)
#pragma unroll
            for (int nt = 0; nt < 4; ++nt)
#pragma unroll
                for (int r = 0; r < 4; ++r) {
                    float sv = s[mt][nt][r] * 0.125f;
                    if (diag) {
                        int key = kb * 64 + nt * 16 + l16;
                        int qrow = rowb + mt * 16 + quad * 4 + r;
                        if (key > qrow) sv = -INFINITY;
                    }
                    s[mt][nt][r] = sv;
                }
        // online softmax (row = mt*16 + quad*4 + r, spread across 16 lanes)
#pragma unroll
        for (int mt = 0; mt < 2; ++mt)
#pragma unroll
            for (int r = 0; r < 4; ++r) {
                float rm = fmaxf(fmaxf(s[mt][0][r], s[mt][1][r]),
                                 fmaxf(s[mt][2][r], s[mt][3][r]));
                rm = fmaxf(rm, __shfl_xor(rm, 1, 16));
                rm = fmaxf(rm, __shfl_xor(rm, 2, 16));
                rm = fmaxf(rm, __shfl_xor(rm, 4, 16));
                rm = fmaxf(rm, __shfl_xor(rm, 8, 16));
                float mNew = fmaxf(mI[mt][r], rm);
                float alpha = __expf(mI[mt][r] - mNew);
                mI[mt][r] = mNew;
                float rs = 0.f;
#pragma unroll
                for (int nt = 0; nt < 4; ++nt) {
                    float p = __expf(s[mt][nt][r] - mNew);
                    s[mt][nt][r] = p;
                    rs += p;
                }
                rs += __shfl_xor(rs, 1, 16);
                rs += __shfl_xor(rs, 2, 16);
                rs += __shfl_xor(rs, 4, 16);
                rs += __shfl_xor(rs, 8, 16);
                lI[mt][r] = lI[mt][r] * alpha + rs;
#pragma unroll
                for (int nt = 0; nt < 4; ++nt) o[mt][nt][r] *= alpha;
            }
        // P -> LDS (per-wave buffer; no barrier needed: same-wave write->read)
#pragma unroll
        for (int mt = 0; mt < 2; ++mt)
#pragma unroll
            for (int nt = 0; nt < 4; ++nt)
#pragma unroll
                for (int r = 0; r < 4; ++r) {
                    int prow = mt * 16 + quad * 4 + r;
                    int col = nt * 16 + l16;
                    int csw = (col >> 3) ^ (prow & 7);
                    Ps[w][prow * 64 + csw * 8 + (col & 7)] = f32_to_bf16(s[mt][nt][r]);
                }
        // O += P V : 16 MFMA
#pragma unroll
        for (int kk = 0; kk < 2; ++kk) {
            bf16x8 af[2];
#pragma unroll
            for (int mt = 0; mt < 2; ++mt)
                af[mt] = *(const bf16x8*)&Ps[w][(mt * 16 + l16) * 64 +
                                                ((kk * 4 + quad) ^ (l16 & 7)) * 8];
#pragma unroll
            for (int nt = 0; nt < 4; ++nt) {
                bf16x8 b = *(const bf16x8*)&VsT[(nt * 16 + l16) * 64 +
                                                ((kk * 4 + quad) ^ (l16 & 7)) * 8];
#pragma unroll
                for (int mt = 0; mt < 2; ++mt)
                    o[mt][nt] = __builtin_amdgcn_mfma_f32_16x16x32_bf16(
                        af[mt], b, o[mt][nt], 0, 0, 0);
            }
        }
    }

    const int bIdx = bh >> 4, h = bh & 15;
#pragma unroll
    for (int mt = 0; mt < 2; ++mt)
#pragma unroll
        for (int r = 0; r < 4; ++r) {
            float inv = 1.0f / lI[mt][r];
            int qrow = rowb + mt * 16 + quad * 4 + r;
#pragma unroll
            for (int nt = 0; nt < 4; ++nt)
                Yatt[((size_t)(bIdx * SEQ + qrow) << 10) + h * 64 + nt * 16 + l16] =
                    f32_to_bf16(o[mt][nt][r] * inv);
        }
}

// ---------------------------------------------------------------- launch
extern "C" void kernel_launch(void* const* d_in, const int* in_sizes, int n_in,
                              void* d_out, int out_size, void* d_ws, size_t ws_size,
                              hipStream_t stream) {
    const float* x = (const float*)d_in[0];
    const float* w_qkv = (const float*)d_in[1];
    const float* b_qkv = (const float*)d_in[2];
    const float* w_proj = (const float*)d_in[3];
    const float* b_proj = (const float*)d_in[4];
    float* out = (float*)d_out;

    char* ws = (char*)d_ws;
    unsigned short* xb     = (unsigned short*)(ws);                       // 16 MB
    unsigned short* wqkvT  = (unsigned short*)(ws + 16777216);            // 6 MB
    unsigned short* wprojT = (unsigned short*)(ws + 23068672);            // 2 MB
    unsigned short* Qb     = (unsigned short*)(ws + 25165824);            // 16 MB
    unsigned short* Kb     = (unsigned short*)(ws + 41943040);            // 16 MB
    unsigned short* Vb     = (unsigned short*)(ws + 58720256);            // 16 MB
    unsigned short* Yatt   = (unsigned short*)(ws + 75497472);            // 16 MB
    unsigned short* Vt     = (unsigned short*)(ws + 92274688);            // 16 MB

    conv_f32_bf16<<<8192, 256, 0, stream>>>(x, xb, (MROWS * DMODEL) / 4);
    transp_conv<<<dim3(96, 32), dim3(32, 8), 0, stream>>>(w_qkv, wqkvT, DMODEL, 3 * DMODEL);
    transp_conv<<<dim3(32, 32), dim3(32, 8), 0, stream>>>(w_proj, wprojT, DMODEL, DMODEL);
    gemm_bt<0><<<dim3(24, 64), 256, 0, stream>>>(xb, wqkvT, b_qkv, nullptr, Qb, Kb, Vb,
                                                 MROWS, 3 * DMODEL, DMODEL);
    transp_bf16_head<<<dim3(2, 64, BATCH * NHEADS), dim3(32, 8), 0, stream>>>(Vb, Vt);
    attn_kernel<<<dim3(SEQ / QCHUNK, BATCH * NHEADS), 256, 0, stream>>>(Qb, Kb, Vt, Yatt);
    gemm_bt<1><<<dim3(8, 64), 256, 0, stream>>>(Yatt, wprojT, b_proj, out, nullptr, nullptr,
                                                nullptr, MROWS, DMODEL, DMODEL);
}

// Round 4
// 451.665 us; speedup vs baseline: 1.3826x; 1.3826x over previous
//
#include <hip/hip_runtime.h>
#include <stdint.h>

#define BATCH 4
#define SEQ 2048
#define DMODEL 1024
#define NHEADS 16
#define HDIM 64
#define MROWS (BATCH * SEQ)   // 8192
#define QCHUNK 128

typedef float floatx4 __attribute__((ext_vector_type(4)));
typedef __bf16 bf16x8 __attribute__((ext_vector_type(8)));
typedef short short8 __attribute__((ext_vector_type(8)));

__device__ __forceinline__ unsigned short f32_to_bf16(float f) {
    union { float f; unsigned int u; } c; c.f = f;
    unsigned int u = c.u;
    unsigned int r = (u + 0x7FFFu + ((u >> 16) & 1u)) >> 16;
    return (unsigned short)r;
}

// async global->LDS 16B per lane (m97 pattern; LDS dest must be lane-linear)
__device__ __forceinline__ void async_ld16(const void* g, void* l) {
    __builtin_amdgcn_global_load_lds(
        (const __attribute__((address_space(1))) unsigned int*)g,
        (__attribute__((address_space(3))) unsigned int*)l, 16, 0, 0);
}

// ---------------------------------------------------------------- convert x
__global__ __launch_bounds__(256) void conv_f32_bf16(
    const float* __restrict__ in, unsigned short* __restrict__ out, int n4) {
    int i = blockIdx.x * 256 + threadIdx.x;
    if (i < n4) {
        float4 v = ((const float4*)in)[i];
        ushort4 o;
        o.x = f32_to_bf16(v.x); o.y = f32_to_bf16(v.y);
        o.z = f32_to_bf16(v.z); o.w = f32_to_bf16(v.w);
        ((ushort4*)out)[i] = o;
    }
}

// ------------------------------------------- transpose+convert W [K,N] -> [N,K] bf16
__global__ __launch_bounds__(256) void transp_conv(
    const float* __restrict__ in, unsigned short* __restrict__ out, int K, int N) {
    __shared__ float tile[32][33];
    int bx = blockIdx.x * 32;  // n
    int by = blockIdx.y * 32;  // k
    int tx = threadIdx.x, ty = threadIdx.y;
#pragma unroll
    for (int i = 0; i < 4; ++i)
        tile[ty + i * 8][tx] = in[(size_t)(by + ty + i * 8) * N + bx + tx];
    __syncthreads();
#pragma unroll
    for (int i = 0; i < 4; ++i)
        out[(size_t)(bx + ty + i * 8) * K + by + tx] = f32_to_bf16(tile[tx][ty + i * 8]);
}

// --------------- per-head bf16 transpose [T,64] -> [64,T], keys PERMUTED within
// each 64-tile: k2 = (k&15)*4 + (k>>4)&3  (must match attn's packed-P layout)
__global__ __launch_bounds__(256) void transp_bf16_head(
    const unsigned short* __restrict__ in, unsigned short* __restrict__ out) {
    __shared__ unsigned short tile[32][33];
    const unsigned short* src = in + (size_t)blockIdx.z * SEQ * HDIM;
    unsigned short* dst = out + (size_t)blockIdx.z * SEQ * HDIM;
    int bx = blockIdx.x * 32;  // d block
    int by = blockIdx.y * 32;  // t block
    int tx = threadIdx.x, ty = threadIdx.y;
#pragma unroll
    for (int i = 0; i < 4; ++i)
        tile[ty + i * 8][tx] = src[(size_t)(by + ty + i * 8) * HDIM + bx + tx];
    __syncthreads();
#pragma unroll
    for (int i = 0; i < 4; ++i) {
        int keyg = by + tx;
        int col2 = (keyg & ~63) | (((keyg & 15) << 2) | ((keyg >> 4) & 3));
        dst[(size_t)(bx + ty + i * 8) * SEQ + col2] = tile[tx][ty + i * 8];
    }
}

// ---------------------------------------------------------------- GEMM (B^T input)
template <int EPI>
__global__ __launch_bounds__(256) void gemm_bt(
    const unsigned short* __restrict__ A, const unsigned short* __restrict__ Bt,
    const float* __restrict__ bias, float* __restrict__ Cout,
    unsigned short* __restrict__ Qo, unsigned short* __restrict__ Ko,
    unsigned short* __restrict__ Vo, int M, int N, int K) {
    __shared__ __align__(16) unsigned short As[128 * 32];
    __shared__ __align__(16) unsigned short Bs[128 * 32];
    const int tid = threadIdx.x;
    const int lane = tid & 63;
    const int w = tid >> 6;
    const int wm = w & 1, wn = w >> 1;
    const int quad = lane >> 4, l16 = lane & 15;
    const int m0 = blockIdx.y * 128;
    const int n0 = blockIdx.x * 128;
    const int fsw = (l16 >> 1) & 3;

    floatx4 acc[4][4];
#pragma unroll
    for (int mt = 0; mt < 4; ++mt)
#pragma unroll
        for (int nt = 0; nt < 4; ++nt) acc[mt][nt] = (floatx4){0.f, 0.f, 0.f, 0.f};

    for (int k0 = 0; k0 < K; k0 += 32) {
#pragma unroll
        for (int r = 0; r < 2; ++r) {
            int idx = tid + r * 256;
            int row = idx >> 2;
            int cg = (idx & 3) ^ ((row >> 1) & 3);
            async_ld16(&A[(size_t)(m0 + row) * K + k0 + cg * 8], &As[idx * 8]);
            async_ld16(&Bt[(size_t)(n0 + row) * K + k0 + cg * 8], &Bs[idx * 8]);
        }
        __syncthreads();
        bf16x8 aF[4], bF[4];
#pragma unroll
        for (int mt = 0; mt < 4; ++mt)
            aF[mt] = *(const bf16x8*)&As[(wm * 64 + mt * 16 + l16) * 32 + (quad ^ fsw) * 8];
#pragma unroll
        for (int nt = 0; nt < 4; ++nt)
            bF[nt] = *(const bf16x8*)&Bs[(wn * 64 + nt * 16 + l16) * 32 + (quad ^ fsw) * 8];
#pragma unroll
        for (int mt = 0; mt < 4; ++mt)
#pragma unroll
            for (int nt = 0; nt < 4; ++nt)
                acc[mt][nt] = __builtin_amdgcn_mfma_f32_16x16x32_bf16(
                    aF[mt], bF[nt], acc[mt][nt], 0, 0, 0);
        __syncthreads();
    }

#pragma unroll
    for (int mt = 0; mt < 4; ++mt)
#pragma unroll
        for (int nt = 0; nt < 4; ++nt)
#pragma unroll
            for (int r = 0; r < 4; ++r) {
                int m = m0 + wm * 64 + mt * 16 + quad * 4 + r;
                int n = n0 + wn * 64 + nt * 16 + l16;
                float v = acc[mt][nt][r] + bias[n];
                if (EPI == 1) {
                    Cout[(size_t)m * N + n] = v;
                } else {
                    int sel = n >> 10, c = n & 1023;
                    int head = c >> 6, d = c & 63;
                    int bb = m >> 11, t = m & 2047;
                    unsigned short* dst = sel == 0 ? Qo : (sel == 1 ? Ko : Vo);
                    dst[((((size_t)bb * NHEADS + head) * SEQ + t) << 6) + d] = f32_to_bf16(v);
                }
            }
}

// ---------------------------------------------------------------- flash attention v3
// BARRIER-FREE: 4 independent waves/block, each owns 32 q-rows. K/V fragments read
// directly from global (L1/L2-resident). P round-trip via per-wave LDS (packed b64,
// key-permuted; Vt pre-permuted to match). Row-sums via MFMA with all-ones B.
__global__ __launch_bounds__(256) void attn_kernel(
    const unsigned short* __restrict__ Qg, const unsigned short* __restrict__ Kg,
    const unsigned short* __restrict__ Vtg, unsigned short* __restrict__ Yatt) {
    __shared__ __align__(16) unsigned short Ps[4][32 * 64];  // 16 KB, per-wave slices

    const int tid = threadIdx.x;
    const int lane = tid & 63;
    const int w = tid >> 6;
    const int quad = lane >> 4, l16 = lane & 15;
    const int qc = (SEQ / QCHUNK - 1) - blockIdx.x;  // heaviest blocks first
    const int q0 = qc * QCHUNK;
    const int bh = blockIdx.y;
    const size_t base = (size_t)bh * SEQ * HDIM;
    const int rowb = q0 + w * 32;
    unsigned short* Pw = &Ps[w][0];

    // Q fragments -> registers
    bf16x8 qf[2][2];
#pragma unroll
    for (int mt = 0; mt < 2; ++mt)
#pragma unroll
        for (int kk = 0; kk < 2; ++kk)
            qf[mt][kk] = *(const bf16x8*)&Qg[base + (size_t)(rowb + mt * 16 + l16) * 64 +
                                             kk * 32 + quad * 8];

    short8 osv = {0x3F80, 0x3F80, 0x3F80, 0x3F80, 0x3F80, 0x3F80, 0x3F80, 0x3F80};
    bf16x8 ones = __builtin_bit_cast(bf16x8, osv);

    float mI[2][4];
    floatx4 lsum[2];
    floatx4 o[2][4];
#pragma unroll
    for (int mt = 0; mt < 2; ++mt) {
        lsum[mt] = (floatx4){0.f, 0.f, 0.f, 0.f};
#pragma unroll
        for (int r = 0; r < 4; ++r) mI[mt][r] = -INFINITY;
#pragma unroll
        for (int nt = 0; nt < 4; ++nt) o[mt][nt] = (floatx4){0.f, 0.f, 0.f, 0.f};
    }

    const int kmaxw = (rowb + 95) >> 6;  // tiles this wave needs

    for (int kb = 0; kb < kmaxw; ++kb) {
        const unsigned short* Kt = Kg + base + (size_t)kb * 64 * HDIM;

        // S = Q K^T : B-frags straight from global
        floatx4 s[2][4];
#pragma unroll
        for (int mt = 0; mt < 2; ++mt)
#pragma unroll
            for (int nt = 0; nt < 4; ++nt) s[mt][nt] = (floatx4){0.f, 0.f, 0.f, 0.f};
#pragma unroll
        for (int kk = 0; kk < 2; ++kk) {
            bf16x8 kf[4];
#pragma unroll
            for (int nt = 0; nt < 4; ++nt)
                kf[nt] = *(const bf16x8*)&Kt[(nt * 16 + l16) * HDIM + kk * 32 + quad * 8];
#pragma unroll
            for (int nt = 0; nt < 4; ++nt)
#pragma unroll
                for (int mt = 0; mt < 2; ++mt)
                    s[mt][nt] = __builtin_amdgcn_mfma_f32_16x16x32_bf16(
                        qf[mt][kk], kf[nt], s[mt][nt], 0, 0, 0);
        }

        const bool diag = (kb * 64 + 63) > rowb;
#pragma unroll
        for (int mt = 0; mt < 2; ++mt)
#pragma unroll
            for (int nt = 0; nt < 4; ++nt)
#pragma unroll
                for (int r = 0; r < 4; ++r) {
                    float sv = s[mt][nt][r] * 0.125f;
                    if (diag) {
                        int key = kb * 64 + nt * 16 + l16;
                        int qrow = rowb + mt * 16 + quad * 4 + r;
                        if (key > qrow) sv = -INFINITY;
                    }
                    s[mt][nt][r] = sv;
                }

        // online softmax: max via shfl; row-sum deferred to MFMA(ones)
#pragma unroll
        for (int mt = 0; mt < 2; ++mt)
#pragma unroll
            for (int r = 0; r < 4; ++r) {
                float rm = fmaxf(fmaxf(s[mt][0][r], s[mt][1][r]),
                                 fmaxf(s[mt][2][r], s[mt][3][r]));
                rm = fmaxf(rm, __shfl_xor(rm, 1, 16));
                rm = fmaxf(rm, __shfl_xor(rm, 2, 16));
                rm = fmaxf(rm, __shfl_xor(rm, 4, 16));
                rm = fmaxf(rm, __shfl_xor(rm, 8, 16));
                float mNew = fmaxf(mI[mt][r], rm);
                float alpha = __expf(mI[mt][r] - mNew);
                mI[mt][r] = mNew;
#pragma unroll
                for (int nt = 0; nt < 4; ++nt)
                    s[mt][nt][r] = __expf(s[mt][nt][r] - mNew);
                lsum[mt][r] *= alpha;
#pragma unroll
                for (int nt = 0; nt < 4; ++nt) o[mt][nt][r] *= alpha;
            }

        // P -> per-wave LDS, packed: lane packs keys {0,16,32,48}+l16 into permuted
        // slots k2 = l16*4+nt; 8B-unit swizzled by (prow&14) for conflict-free b128 read
#pragma unroll
        for (int mt = 0; mt < 2; ++mt)
#pragma unroll
            for (int r = 0; r < 4; ++r) {
                int prow = mt * 16 + quad * 4 + r;
                int unit = l16 ^ (prow & 14);
                ushort4 pv;
                pv.x = f32_to_bf16(s[mt][0][r]);
                pv.y = f32_to_bf16(s[mt][1][r]);
                pv.z = f32_to_bf16(s[mt][2][r]);
                pv.w = f32_to_bf16(s[mt][3][r]);
                *(ushort4*)&Pw[prow * 64 + unit * 4] = pv;
            }

        // O += P V ; l += P 1   (V^T pre-permuted to the same key order)
        const unsigned short* Vt = Vtg + base + kb * 64;
#pragma unroll
        for (int kk = 0; kk < 2; ++kk) {
            bf16x8 af[2];
#pragma unroll
            for (int mt = 0; mt < 2; ++mt) {
                int prow = mt * 16 + l16;
                int u2 = (kk * 8 + quad * 2) ^ (l16 & 14);  // FIX: kk*8 term was missing
                af[mt] = *(const bf16x8*)&Pw[prow * 64 + u2 * 4];
            }
#pragma unroll
            for (int nt = 0; nt < 4; ++nt) {
                bf16x8 vf = *(const bf16x8*)&Vt[(size_t)(nt * 16 + l16) * SEQ +
                                                kk * 32 + quad * 8];
#pragma unroll
                for (int mt = 0; mt < 2; ++mt)
                    o[mt][nt] = __builtin_amdgcn_mfma_f32_16x16x32_bf16(
                        af[mt], vf, o[mt][nt], 0, 0, 0);
            }
#pragma unroll
            for (int mt = 0; mt < 2; ++mt)
                lsum[mt] = __builtin_amdgcn_mfma_f32_16x16x32_bf16(
                    af[mt], ones, lsum[mt], 0, 0, 0);
        }
    }

    const int bIdx = bh >> 4, h = bh & 15;
#pragma unroll
    for (int mt = 0; mt < 2; ++mt)
#pragma unroll
        for (int r = 0; r < 4; ++r) {
            float inv = 1.0f / lsum[mt][r];
            int qrow = rowb + mt * 16 + quad * 4 + r;
#pragma unroll
            for (int nt = 0; nt < 4; ++nt)
                Yatt[((size_t)(bIdx * SEQ + qrow) << 10) + h * 64 + nt * 16 + l16] =
                    f32_to_bf16(o[mt][nt][r] * inv);
        }
}

// ---------------------------------------------------------------- launch
extern "C" void kernel_launch(void* const* d_in, const int* in_sizes, int n_in,
                              void* d_out, int out_size, void* d_ws, size_t ws_size,
                              hipStream_t stream) {
    const float* x = (const float*)d_in[0];
    const float* w_qkv = (const float*)d_in[1];
    const float* b_qkv = (const float*)d_in[2];
    const float* w_proj = (const float*)d_in[3];
    const float* b_proj = (const float*)d_in[4];
    float* out = (float*)d_out;

    char* ws = (char*)d_ws;
    unsigned short* xb     = (unsigned short*)(ws);                       // 16 MB
    unsigned short* wqkvT  = (unsigned short*)(ws + 16777216);            // 6 MB
    unsigned short* wprojT = (unsigned short*)(ws + 23068672);            // 2 MB
    unsigned short* Qb     = (unsigned short*)(ws + 25165824);            // 16 MB
    unsigned short* Kb     = (unsigned short*)(ws + 41943040);            // 16 MB
    unsigned short* Vb     = (unsigned short*)(ws + 58720256);            // 16 MB
    unsigned short* Yatt   = (unsigned short*)(ws + 75497472);            // 16 MB
    unsigned short* Vt     = (unsigned short*)(ws + 92274688);            // 16 MB

    conv_f32_bf16<<<8192, 256, 0, stream>>>(x, xb, (MROWS * DMODEL) / 4);
    transp_conv<<<dim3(96, 32), dim3(32, 8), 0, stream>>>(w_qkv, wqkvT, DMODEL, 3 * DMODEL);
    transp_conv<<<dim3(32, 32), dim3(32, 8), 0, stream>>>(w_proj, wprojT, DMODEL, DMODEL);
    gemm_bt<0><<<dim3(24, 64), 256, 0, stream>>>(xb, wqkvT, b_qkv, nullptr, Qb, Kb, Vb,
                                                 MROWS, 3 * DMODEL, DMODEL);
    transp_bf16_head<<<dim3(2, 64, BATCH * NHEADS), dim3(32, 8), 0, stream>>>(Vb, Vt);
    attn_kernel<<<dim3(SEQ / QCHUNK, BATCH * NHEADS), 256, 0, stream>>>(Qb, Kb, Vt, Yatt);
    gemm_bt<1><<<dim3(8, 64), 256, 0, stream>>>(Yatt, wprojT, b_proj, out, nullptr, nullptr,
                                                nullptr, MROWS, DMODEL, DMODEL);
}

// Round 6
// 359.261 us; speedup vs baseline: 1.7382x; 1.2572x over previous
//
#include <hip/hip_runtime.h>
#include <stdint.h>

#define BATCH 4
#define SEQ 2048
#define DMODEL 1024
#define NHEADS 16
#define HDIM 64
#define MROWS (BATCH * SEQ)   // 8192

typedef float floatx4 __attribute__((ext_vector_type(4)));
typedef __bf16 bf16x8 __attribute__((ext_vector_type(8)));
typedef short short8 __attribute__((ext_vector_type(8)));

__device__ __forceinline__ unsigned short f32_to_bf16(float f) {
    union { float f; unsigned int u; } c; c.f = f;
    unsigned int u = c.u;
    unsigned int r = (u + 0x7FFFu + ((u >> 16) & 1u)) >> 16;
    return (unsigned short)r;
}

// async global->LDS 16B per lane (m97 pattern; LDS dest must be lane-linear)
__device__ __forceinline__ void async_ld16(const void* g, void* l) {
    __builtin_amdgcn_global_load_lds(
        (const __attribute__((address_space(1))) unsigned int*)g,
        (__attribute__((address_space(3))) unsigned int*)l, 16, 0, 0);
}

// ---------------------------------------------------------------- convert x
__global__ __launch_bounds__(256) void conv_f32_bf16(
    const float* __restrict__ in, unsigned short* __restrict__ out, int n4) {
    int i = blockIdx.x * 256 + threadIdx.x;
    if (i < n4) {
        float4 v = ((const float4*)in)[i];
        ushort4 o;
        o.x = f32_to_bf16(v.x); o.y = f32_to_bf16(v.y);
        o.z = f32_to_bf16(v.z); o.w = f32_to_bf16(v.w);
        ((ushort4*)out)[i] = o;
    }
}

// ------------------------------------------- transpose+convert W [K,N] -> [N,K] bf16
__global__ __launch_bounds__(256) void transp_conv(
    const float* __restrict__ in, unsigned short* __restrict__ out, int K, int N) {
    __shared__ float tile[32][33];
    int bx = blockIdx.x * 32;  // n
    int by = blockIdx.y * 32;  // k
    int tx = threadIdx.x, ty = threadIdx.y;
#pragma unroll
    for (int i = 0; i < 4; ++i)
        tile[ty + i * 8][tx] = in[(size_t)(by + ty + i * 8) * N + bx + tx];
    __syncthreads();
#pragma unroll
    for (int i = 0; i < 4; ++i)
        out[(size_t)(bx + ty + i * 8) * K + by + tx] = f32_to_bf16(tile[tx][ty + i * 8]);
}

// --------------- per-head bf16 transpose [T,64] -> [64,T], keys PERMUTED within
// each 64-tile: k2 = (k&15)*4 + (k>>4)&3  (must match attn's packed-P layout)
__global__ __launch_bounds__(256) void transp_bf16_head(
    const unsigned short* __restrict__ in, unsigned short* __restrict__ out) {
    __shared__ unsigned short tile[32][33];
    const unsigned short* src = in + (size_t)blockIdx.z * SEQ * HDIM;
    unsigned short* dst = out + (size_t)blockIdx.z * SEQ * HDIM;
    int bx = blockIdx.x * 32;  // d block
    int by = blockIdx.y * 32;  // t block
    int tx = threadIdx.x, ty = threadIdx.y;
#pragma unroll
    for (int i = 0; i < 4; ++i)
        tile[ty + i * 8][tx] = src[(size_t)(by + ty + i * 8) * HDIM + bx + tx];
    __syncthreads();
#pragma unroll
    for (int i = 0; i < 4; ++i) {
        int keyg = by + tx;
        int col2 = (keyg & ~63) | (((keyg & 15) << 2) | ((keyg >> 4) & 3));
        dst[(size_t)(bx + ty + i * 8) * SEQ + col2] = tile[tx][ty + i * 8];
    }
}

// ---------------------------------------------------------------- GEMM (B^T input)
template <int EPI>
__global__ __launch_bounds__(256) void gemm_bt(
    const unsigned short* __restrict__ A, const unsigned short* __restrict__ Bt,
    const float* __restrict__ bias, float* __restrict__ Cout,
    unsigned short* __restrict__ Qo, unsigned short* __restrict__ Ko,
    unsigned short* __restrict__ Vo, int M, int N, int K) {
    __shared__ __align__(16) unsigned short As[128 * 32];
    __shared__ __align__(16) unsigned short Bs[128 * 32];
    const int tid = threadIdx.x;
    const int lane = tid & 63;
    const int w = tid >> 6;
    const int wm = w & 1, wn = w >> 1;
    const int quad = lane >> 4, l16 = lane & 15;
    const int m0 = blockIdx.y * 128;
    const int n0 = blockIdx.x * 128;
    const int fsw = (l16 >> 1) & 3;

    floatx4 acc[4][4];
#pragma unroll
    for (int mt = 0; mt < 4; ++mt)
#pragma unroll
        for (int nt = 0; nt < 4; ++nt) acc[mt][nt] = (floatx4){0.f, 0.f, 0.f, 0.f};

    for (int k0 = 0; k0 < K; k0 += 32) {
#pragma unroll
        for (int r = 0; r < 2; ++r) {
            int idx = tid + r * 256;
            int row = idx >> 2;
            int cg = (idx & 3) ^ ((row >> 1) & 3);
            async_ld16(&A[(size_t)(m0 + row) * K + k0 + cg * 8], &As[idx * 8]);
            async_ld16(&Bt[(size_t)(n0 + row) * K + k0 + cg * 8], &Bs[idx * 8]);
        }
        __syncthreads();
        bf16x8 aF[4], bF[4];
#pragma unroll
        for (int mt = 0; mt < 4; ++mt)
            aF[mt] = *(const bf16x8*)&As[(wm * 64 + mt * 16 + l16) * 32 + (quad ^ fsw) * 8];
#pragma unroll
        for (int nt = 0; nt < 4; ++nt)
            bF[nt] = *(const bf16x8*)&Bs[(wn * 64 + nt * 16 + l16) * 32 + (quad ^ fsw) * 8];
#pragma unroll
        for (int mt = 0; mt < 4; ++mt)
#pragma unroll
            for (int nt = 0; nt < 4; ++nt)
                acc[mt][nt] = __builtin_amdgcn_mfma_f32_16x16x32_bf16(
                    aF[mt], bF[nt], acc[mt][nt], 0, 0, 0);
        __syncthreads();
    }

#pragma unroll
    for (int mt = 0; mt < 4; ++mt)
#pragma unroll
        for (int nt = 0; nt < 4; ++nt)
#pragma unroll
            for (int r = 0; r < 4; ++r) {
                int m = m0 + wm * 64 + mt * 16 + quad * 4 + r;
                int n = n0 + wn * 64 + nt * 16 + l16;
                float v = acc[mt][nt][r] + bias[n];
                if (EPI == 1) {
                    Cout[(size_t)m * N + n] = v;
                } else {
                    int sel = n >> 10, c = n & 1023;
                    int head = c >> 6, d = c & 63;
                    int bb = m >> 11, t = m & 2047;
                    unsigned short* dst = sel == 0 ? Qo : (sel == 1 ? Ko : Vo);
                    dst[((((size_t)bb * NHEADS + head) * SEQ + t) << 6) + d] = f32_to_bf16(v);
                }
            }
}

// ---------------------------------------------------------------- flash attention v5
// R4 kernel + uniform-work strip pairing ONLY: wave handles strip s (32 q-rows) then
// mirror strip 63-s -> 33-34 key-tiles for EVERY wave. All numerics identical to R4.
__global__ __launch_bounds__(256) void attn_kernel(
    const unsigned short* __restrict__ Qg, const unsigned short* __restrict__ Kg,
    const unsigned short* __restrict__ Vtg, unsigned short* __restrict__ Yatt) {
    __shared__ __align__(16) unsigned short Ps[4][32 * 64];  // 16 KB, per-wave slices

    const int tid = threadIdx.x;
    const int lane = tid & 63;
    const int w = tid >> 6;
    const int quad = lane >> 4, l16 = lane & 15;
    const int sA = blockIdx.x * 4 + w;  // strip 0..31 (mirror = 63-sA)
    const int bh = blockIdx.y;
    const size_t base = (size_t)bh * SEQ * HDIM;
    const int bIdx = bh >> 4, h = bh & 15;
    unsigned short* Pw = &Ps[w][0];

    short8 osv = {0x3F80, 0x3F80, 0x3F80, 0x3F80, 0x3F80, 0x3F80, 0x3F80, 0x3F80};
    bf16x8 ones = __builtin_bit_cast(bf16x8, osv);

    for (int half = 0; half < 2; ++half) {
        const int rowb = (half == 0 ? sA : 63 - sA) * 32;

        // Q fragments -> registers
        bf16x8 qf[2][2];
#pragma unroll
        for (int mt = 0; mt < 2; ++mt)
#pragma unroll
            for (int kk = 0; kk < 2; ++kk)
                qf[mt][kk] = *(const bf16x8*)&Qg[base + (size_t)(rowb + mt * 16 + l16) * 64 +
                                                 kk * 32 + quad * 8];

        float mI[2][4];
        floatx4 lsum[2];
        floatx4 o[2][4];
#pragma unroll
        for (int mt = 0; mt < 2; ++mt) {
            lsum[mt] = (floatx4){0.f, 0.f, 0.f, 0.f};
#pragma unroll
            for (int r = 0; r < 4; ++r) mI[mt][r] = -INFINITY;
#pragma unroll
            for (int nt = 0; nt < 4; ++nt) o[mt][nt] = (floatx4){0.f, 0.f, 0.f, 0.f};
        }

        const int kmaxw = (rowb + 95) >> 6;

        for (int kb = 0; kb < kmaxw; ++kb) {
            const unsigned short* Kt = Kg + base + (size_t)kb * 64 * HDIM;

            // S = Q K^T : B-frags straight from global
            floatx4 s[2][4];
#pragma unroll
            for (int mt = 0; mt < 2; ++mt)
#pragma unroll
                for (int nt = 0; nt < 4; ++nt) s[mt][nt] = (floatx4){0.f, 0.f, 0.f, 0.f};
#pragma unroll
            for (int kk = 0; kk < 2; ++kk) {
                bf16x8 kf[4];
#pragma unroll
                for (int nt = 0; nt < 4; ++nt)
                    kf[nt] = *(const bf16x8*)&Kt[(nt * 16 + l16) * HDIM + kk * 32 + quad * 8];
#pragma unroll
                for (int nt = 0; nt < 4; ++nt)
#pragma unroll
                    for (int mt = 0; mt < 2; ++mt)
                        s[mt][nt] = __builtin_amdgcn_mfma_f32_16x16x32_bf16(
                            qf[mt][kk], kf[nt], s[mt][nt], 0, 0, 0);
            }

            const bool diag = (kb * 64 + 63) > rowb;
#pragma unroll
            for (int mt = 0; mt < 2; ++mt)
#pragma unroll
                for (int nt = 0; nt < 4; ++nt)
#pragma unroll
                    for (int r = 0; r < 4; ++r) {
                        float sv = s[mt][nt][r] * 0.125f;
                        if (diag) {
                            int key = kb * 64 + nt * 16 + l16;
                            int qrow = rowb + mt * 16 + quad * 4 + r;
                            if (key > qrow) sv = -INFINITY;
                        }
                        s[mt][nt][r] = sv;
                    }

            // online softmax: max via shfl; row-sum deferred to MFMA(ones)
#pragma unroll
            for (int mt = 0; mt < 2; ++mt)
#pragma unroll
                for (int r = 0; r < 4; ++r) {
                    float rm = fmaxf(fmaxf(s[mt][0][r], s[mt][1][r]),
                                     fmaxf(s[mt][2][r], s[mt][3][r]));
                    rm = fmaxf(rm, __shfl_xor(rm, 1, 16));
                    rm = fmaxf(rm, __shfl_xor(rm, 2, 16));
                    rm = fmaxf(rm, __shfl_xor(rm, 4, 16));
                    rm = fmaxf(rm, __shfl_xor(rm, 8, 16));
                    float mNew = fmaxf(mI[mt][r], rm);
                    float alpha = __expf(mI[mt][r] - mNew);
                    mI[mt][r] = mNew;
#pragma unroll
                    for (int nt = 0; nt < 4; ++nt)
                        s[mt][nt][r] = __expf(s[mt][nt][r] - mNew);
                    lsum[mt][r] *= alpha;
#pragma unroll
                    for (int nt = 0; nt < 4; ++nt) o[mt][nt][r] *= alpha;
                }

            // P -> per-wave LDS, packed slots k2 = l16*4+nt; swizzled by (prow&14)
#pragma unroll
            for (int mt = 0; mt < 2; ++mt)
#pragma unroll
                for (int r = 0; r < 4; ++r) {
                    int prow = mt * 16 + quad * 4 + r;
                    int unit = l16 ^ (prow & 14);
                    ushort4 pv;
                    pv.x = f32_to_bf16(s[mt][0][r]);
                    pv.y = f32_to_bf16(s[mt][1][r]);
                    pv.z = f32_to_bf16(s[mt][2][r]);
                    pv.w = f32_to_bf16(s[mt][3][r]);
                    *(ushort4*)&Pw[prow * 64 + unit * 4] = pv;
                }

            // O += P V ; l += P 1   (V^T pre-permuted to packed key order)
            const unsigned short* Vt = Vtg + base + kb * 64;
#pragma unroll
            for (int kk = 0; kk < 2; ++kk) {
                bf16x8 af[2];
#pragma unroll
                for (int mt = 0; mt < 2; ++mt) {
                    int prow = mt * 16 + l16;
                    int u2 = (kk * 8 + quad * 2) ^ (l16 & 14);
                    af[mt] = *(const bf16x8*)&Pw[prow * 64 + u2 * 4];
                }
#pragma unroll
                for (int nt = 0; nt < 4; ++nt) {
                    bf16x8 vf = *(const bf16x8*)&Vt[(size_t)(nt * 16 + l16) * SEQ +
                                                    kk * 32 + quad * 8];
#pragma unroll
                    for (int mt = 0; mt < 2; ++mt)
                        o[mt][nt] = __builtin_amdgcn_mfma_f32_16x16x32_bf16(
                            af[mt], vf, o[mt][nt], 0, 0, 0);
                }
#pragma unroll
                for (int mt = 0; mt < 2; ++mt)
                    lsum[mt] = __builtin_amdgcn_mfma_f32_16x16x32_bf16(
                        af[mt], ones, lsum[mt], 0, 0, 0);
            }
        }

#pragma unroll
        for (int mt = 0; mt < 2; ++mt)
#pragma unroll
            for (int r = 0; r < 4; ++r) {
                float inv = 1.0f / lsum[mt][r];
                int qrow = rowb + mt * 16 + quad * 4 + r;
#pragma unroll
                for (int nt = 0; nt < 4; ++nt)
                    Yatt[((size_t)(bIdx * SEQ + qrow) << 10) + h * 64 + nt * 16 + l16] =
                        f32_to_bf16(o[mt][nt][r] * inv);
            }
    }
}

// ---------------------------------------------------------------- launch
extern "C" void kernel_launch(void* const* d_in, const int* in_sizes, int n_in,
                              void* d_out, int out_size, void* d_ws, size_t ws_size,
                              hipStream_t stream) {
    const float* x = (const float*)d_in[0];
    const float* w_qkv = (const float*)d_in[1];
    const float* b_qkv = (const float*)d_in[2];
    const float* w_proj = (const float*)d_in[3];
    const float* b_proj = (const float*)d_in[4];
    float* out = (float*)d_out;

    char* ws = (char*)d_ws;
    unsigned short* xb     = (unsigned short*)(ws);                       // 16 MB
    unsigned short* wqkvT  = (unsigned short*)(ws + 16777216);            // 6 MB
    unsigned short* wprojT = (unsigned short*)(ws + 23068672);            // 2 MB
    unsigned short* Qb     = (unsigned short*)(ws + 25165824);            // 16 MB
    unsigned short* Kb     = (unsigned short*)(ws + 41943040);            // 16 MB
    unsigned short* Vb     = (unsigned short*)(ws + 58720256);            // 16 MB
    unsigned short* Yatt   = (unsigned short*)(ws + 75497472);            // 16 MB
    unsigned short* Vt     = (unsigned short*)(ws + 92274688);            // 16 MB

    conv_f32_bf16<<<8192, 256, 0, stream>>>(x, xb, (MROWS * DMODEL) / 4);
    transp_conv<<<dim3(96, 32), dim3(32, 8), 0, stream>>>(w_qkv, wqkvT, DMODEL, 3 * DMODEL);
    transp_conv<<<dim3(32, 32), dim3(32, 8), 0, stream>>>(w_proj, wprojT, DMODEL, DMODEL);
    gemm_bt<0><<<dim3(24, 64), 256, 0, stream>>>(xb, wqkvT, b_qkv, nullptr, Qb, Kb, Vb,
                                                 MROWS, 3 * DMODEL, DMODEL);
    transp_bf16_head<<<dim3(2, 64, BATCH * NHEADS), dim3(32, 8), 0, stream>>>(Vb, Vt);
    attn_kernel<<<dim3(8, 64), 256, 0, stream>>>(Qb, Kb, Vt, Yatt);
    gemm_bt<1><<<dim3(8, 64), 256, 0, stream>>>(Yatt, wprojT, b_proj, out, nullptr, nullptr,
                                                nullptr, MROWS, DMODEL, DMODEL);
}